// Round 5
// baseline (495.722 us; speedup 1.0000x reference)
//
#include <hip/hip_runtime.h>
#include <hip/hip_bf16.h>

typedef __attribute__((ext_vector_type(8))) short bf16x8;
typedef __attribute__((ext_vector_type(4))) float f32x4;
typedef __attribute__((address_space(1))) const void glob_cv;
typedef __attribute__((address_space(3))) void lds_v;

constexpr int N_ = 4096, D_ = 512, C_ = 50000;
constexpr float S_ = 30.0f, M_ = 0.4f, EPS_ = 1e-7f;

#define WAITVM(N) asm volatile("s_waitcnt vmcnt(" #N ")" ::: "memory")
#define SBAR() do { __builtin_amdgcn_sched_barrier(0); __builtin_amdgcn_s_barrier(); __builtin_amdgcn_sched_barrier(0); } while (0)

__device__ inline ushort f2bf(float f) {
  unsigned u = __builtin_bit_cast(unsigned, f);
  u += 0x7fffu + ((u >> 16) & 1u);
  return (ushort)(u >> 16);
}

// ---------------- 0) convert W fp32 -> bf16 (one pass) ----------------
__global__ __launch_bounds__(256) void convw_kernel(const float* __restrict__ W,
                                                    ushort* __restrict__ Wb) {
  const long total = (long)C_ * D_ / 8;
  const long stride = (long)gridDim.x * 256;
  for (long k = (long)blockIdx.x * 256 + threadIdx.x; k < total; k += stride) {
    float4 a = reinterpret_cast<const float4*>(W)[2 * k];
    float4 b = reinterpret_cast<const float4*>(W)[2 * k + 1];
    union { ushort u[8]; uint4 v; } pk;
    pk.u[0] = f2bf(a.x); pk.u[1] = f2bf(a.y); pk.u[2] = f2bf(a.z); pk.u[3] = f2bf(a.w);
    pk.u[4] = f2bf(b.x); pk.u[5] = f2bf(b.y); pk.u[6] = f2bf(b.z); pk.u[7] = f2bf(b.w);
    reinterpret_cast<uint4*>(Wb)[k] = pk.v;
  }
}

// ---------------- 1) row L2-normalize x -> bf16 ----------------
__global__ __launch_bounds__(256) void norm_kernel(const float* __restrict__ x,
                                                   ushort* __restrict__ xnb) {
  const int wid = threadIdx.x >> 6;
  const int lane = threadIdx.x & 63;
  const int row = blockIdx.x * 4 + wid;
  const float4* xr = reinterpret_cast<const float4*>(x + (size_t)row * D_);
  float4 a = xr[lane * 2];
  float4 b = xr[lane * 2 + 1];
  float ss = a.x * a.x + a.y * a.y + a.z * a.z + a.w * a.w +
             b.x * b.x + b.y * b.y + b.z * b.z + b.w * b.w;
#pragma unroll
  for (int m = 1; m < 64; m <<= 1) ss += __shfl_xor(ss, m);
  const float inv = 1.0f / sqrtf(ss);
  union { ushort u[8]; uint4 v; } pk;
  pk.u[0] = f2bf(a.x * inv); pk.u[1] = f2bf(a.y * inv);
  pk.u[2] = f2bf(a.z * inv); pk.u[3] = f2bf(a.w * inv);
  pk.u[4] = f2bf(b.x * inv); pk.u[5] = f2bf(b.y * inv);
  pk.u[6] = f2bf(b.z * inv); pk.u[7] = f2bf(b.w * inv);
  reinterpret_cast<uint4*>(xnb + (size_t)row * D_)[lane] = pk.v;
}

// ---------------- 2a) 8-phase 256x256 GEMM (T2+T3+T4+T5) ----------------
// 512 threads = 8 waves (2M x 4N), wave tile 128x64. BK=64, K-tiles 0..7.
// LDS: 8 slots of 16 KB: slot(buf,op,kh) = 256 rows x 32 k-elems (64 B rows),
// XOR-swizzled kb ^= ((r>>1)&3)<<4 via pre-swizzled global source (rule #21).
// Phase p of iter i (K-tiles 2i,2i+1):
//   ph0..3 compute buf0 (k0 m0, k0 m1, k1 m0, k1 m1); ph4..7 compute buf1.
//   staging: ph0,1 -> buf1.k1 (tile 2i+1); ph2..5 -> buf0 (tile 2i+2);
//            ph6,7 -> buf1.k0 (tile 2i+3).   1 slot (2 gload_lds) per phase.
//   WAITVM(4) only at end of ph3 and ph7: retires exactly the 8 loads of the
//   buffer consumed next, leaves 4 in flight. Never drains mid-loop.
__global__ __launch_bounds__(512, 2) void gemm_8ph(
    const ushort* __restrict__ A,         // xn bf16 [N][D]
    const ushort* __restrict__ Wb,        // bf16 [C][D]
    const int* __restrict__ target,
    float* __restrict__ row_sum,
    float* __restrict__ tgt_logit) {
  __shared__ char S[131072];              // [buf][op][kh]: buf*65536+op*32768+kh*16384
  __shared__ int tgt_s[256];

  const int t = threadIdx.x, lane = t & 63, wid = t >> 6;
  const int wr = wid >> 2, wc = wid & 3;   // 2M x 4N

  // bijective XCD swizzle: 3136 blocks, 392 per XCD; bx fastest within chunk
  const int orig = blockIdx.y * 16 + blockIdx.x;
  const int swz = (orig & 7) * 392 + (orig >> 3);
  const int row0 = (swz & 15) * 256, col0 = (swz >> 4) * 256;

  // staging: lane covers row r = j*128 + wid*16 + (lane>>2), 16 B at kb=(lane&3)*16;
  // source k-elem pre-swizzled so LDS[r][kb] holds elems ((kb/16)^((r>>1)&3))*8..+7
  const int ke = ((lane & 3) ^ ((lane >> 3) & 3)) << 3;
  const int kb0 = (lane >> 4) << 4;       // read-side 16B quarter

  auto STG = [&](int T, int kh, int isB, int buf) {
    char* dst = S + buf * 65536 + isB * 32768 + kh * 16384 + wid * 1024;
#pragma unroll
    for (int j = 0; j < 2; ++j) {
      const int r = j * 128 + wid * 16 + (lane >> 2);
      const ushort* src;
      if (isB) {
        const int gc = col0 + r;
        src = Wb + (size_t)(gc < C_ ? gc : 0) * D_ + T * 64 + kh * 32 + ke;
      } else {
        src = A + (size_t)(row0 + r) * D_ + T * 64 + kh * 32 + ke;
      }
      __builtin_amdgcn_global_load_lds((glob_cv*)src, (lds_v*)(dst + j * 8192), 16, 0, 0);
    }
  };

  f32x4 acc[8][4] = {};
  bf16x8 bf[4];

  // phase body. wk: 0 = no wait, 1 = WAITVM(4), 2 = WAITVM(0)
  auto PHASE = [&](int buf, int kh, int mh, auto stageFn, int wk) {
    if (mh == 0) {
      const char* Bb = S + buf * 65536 + 32768 + kh * 16384;
#pragma unroll
      for (int n = 0; n < 4; ++n) {
        const int rc = wc * 64 + n * 16 + (lane & 15);
        bf[n] = *reinterpret_cast<const bf16x8*>(Bb + rc * 64 + (kb0 ^ (((rc >> 1) & 3) << 4)));
      }
    }
    const char* Ab = S + buf * 65536 + kh * 16384;
    bf16x8 af[4];
#pragma unroll
    for (int mi = 0; mi < 4; ++mi) {
      const int rr = wr * 128 + mh * 64 + mi * 16 + (lane & 15);
      af[mi] = *reinterpret_cast<const bf16x8*>(Ab + rr * 64 + (kb0 ^ (((rr >> 1) & 3) << 4)));
    }
    stageFn();
    SBAR();                                // all slots for this phase staged+landed
    __builtin_amdgcn_s_setprio(1);
#pragma unroll
    for (int mi = 0; mi < 4; ++mi)
#pragma unroll
      for (int n = 0; n < 4; ++n)
        acc[mh * 4 + mi][n] =
            __builtin_amdgcn_mfma_f32_16x16x32_bf16(af[mi], bf[n], acc[mh * 4 + mi][n], 0, 0, 0);
    __builtin_amdgcn_s_setprio(0);
    if (wk == 1) { WAITVM(4); }
    else if (wk == 2) { WAITVM(0); }
    SBAR();                                // frees the slots this phase read
  };

  // prologue: buf0 <- tile 0 (4 slots), buf1.k0 <- tile 1 (2 slots) = 12 loads
  STG(0, 0, 0, 0); STG(0, 0, 1, 0); STG(0, 1, 0, 0); STG(0, 1, 1, 0);
  STG(1, 0, 0, 1); STG(1, 0, 1, 1);
  WAITVM(4);                               // buf0 fully landed (mine); buf1.k0 in flight
  SBAR();

#pragma unroll
  for (int i = 0; i < 4; ++i) {
    PHASE(0, 0, 0, [&] { STG(2 * i + 1, 1, 0, 1); }, 0);
    PHASE(0, 0, 1, [&] { STG(2 * i + 1, 1, 1, 1); }, 0);
    PHASE(0, 1, 0, [&] { if (i < 3) STG(2 * i + 2, 0, 0, 0); }, 0);
    PHASE(0, 1, 1, [&] { if (i < 3) STG(2 * i + 2, 0, 1, 0); }, i < 3 ? 1 : 2);
    PHASE(1, 0, 0, [&] { if (i < 3) STG(2 * i + 2, 1, 0, 0); }, 0);
    PHASE(1, 0, 1, [&] { if (i < 3) STG(2 * i + 2, 1, 1, 0); }, 0);
    PHASE(1, 1, 0, [&] { if (i < 3) STG(2 * i + 3, 0, 0, 1); }, 0);
    PHASE(1, 1, 1, [&] { if (i < 3) STG(2 * i + 3, 0, 1, 1); }, i < 3 ? 1 : 2);
  }

  // targets for this row-block (post-loop: keeps vmcnt ordinals clean in-loop)
  if (t < 256) tgt_s[t] = target[row0 + t];
  __syncthreads();

  // epilogue: exp-sum per row + target extraction. C/D: col=lane&15, row=(lane>>4)*4+j
#pragma unroll
  for (int mm = 0; mm < 8; ++mm) {
#pragma unroll
    for (int j = 0; j < 4; ++j) {
      const int lr = wr * 128 + mm * 16 + ((lane >> 4) << 2) + j;
      const int grow = row0 + lr;
      const int trow = tgt_s[lr];
      float s = 0.f;
#pragma unroll
      for (int n = 0; n < 4; ++n) {
        const int gcol = col0 + wc * 64 + n * 16 + (lane & 15);
        const float v = acc[mm][n][j];
        if (gcol < C_) s += __expf(S_ * v);
        if (gcol == trow) tgt_logit[grow] = v;
      }
      s += __shfl_xor(s, 1); s += __shfl_xor(s, 2);
      s += __shfl_xor(s, 4); s += __shfl_xor(s, 8);
      if ((lane & 15) == 0) atomicAdd(&row_sum[grow], s);
    }
  }
}

// ---------------- 2b) fallback GEMM (round-2 proven, fp32 W in-loop convert) ----------------
__global__ __launch_bounds__(256) void gemm_kernel(
    const ushort* __restrict__ A, const float* __restrict__ W,
    const int* __restrict__ target, float* __restrict__ row_sum,
    float* __restrict__ tgt_logit) {
  constexpr int BM = 128, BN = 128, BK = 64;
  __shared__ char As[BM * BK * 2];
  __shared__ char Bs[BN * BK * 2];
  __shared__ int tgt_s[BM];
  const int t = threadIdx.x;
  const int lane = t & 63, wid = t >> 6;
  const int wr = wid >> 1, wc = wid & 1;
  const int row0 = blockIdx.x * BM;
  const int col0 = blockIdx.y * BN;
  if (t < BM) tgt_s[t] = target[row0 + t];
  f32x4 acc[4][4] = {};
  for (int kt = 0; kt < D_ / BK; ++kt) {
    __syncthreads();
#pragma unroll
    for (int i = 0; i < 4; ++i) {
      const int L = i * 4096 + t * 16;
      const int r = L >> 7, kb = L & 127;
      const char* gsrc = reinterpret_cast<const char*>(A) +
                         (size_t)(row0 + r) * (D_ * 2) + kt * (BK * 2) + kb;
      uint4 v = *reinterpret_cast<const uint4*>(gsrc);
      *reinterpret_cast<uint4*>(As + r * 128 + (kb ^ ((r & 7) << 4))) = v;
    }
#pragma unroll
    for (int j = 0; j < 8; ++j) {
      const int flat = j * 256 + t;
      const int c = flat >> 4, kq = flat & 15;
      const int gc = col0 + c;
      float4 v = make_float4(0.f, 0.f, 0.f, 0.f);
      if (gc < C_)
        v = *reinterpret_cast<const float4*>(W + (size_t)gc * D_ + kt * BK + kq * 4);
      ushort4 h;
      h.x = f2bf(v.x); h.y = f2bf(v.y); h.z = f2bf(v.z); h.w = f2bf(v.w);
      const int kb = kq * 8;
      *reinterpret_cast<ushort4*>(Bs + c * 128 + (kb ^ ((c & 7) << 4))) = h;
    }
    __syncthreads();
#pragma unroll
    for (int h = 0; h < 2; ++h) {
      const int kbh = h * 64 + ((lane >> 4) << 4);
      bf16x8 af[4], bfr[4];
#pragma unroll
      for (int m = 0; m < 4; ++m) {
        const int r = wr * 64 + m * 16 + (lane & 15);
        af[m] = *reinterpret_cast<const bf16x8*>(As + r * 128 + (kbh ^ ((r & 7) << 4)));
      }
#pragma unroll
      for (int n = 0; n < 4; ++n) {
        const int c = wc * 64 + n * 16 + (lane & 15);
        bfr[n] = *reinterpret_cast<const bf16x8*>(Bs + c * 128 + (kbh ^ ((c & 7) << 4)));
      }
#pragma unroll
      for (int m = 0; m < 4; ++m)
#pragma unroll
        for (int n = 0; n < 4; ++n)
          acc[m][n] = __builtin_amdgcn_mfma_f32_16x16x32_bf16(af[m], bfr[n], acc[m][n], 0, 0, 0);
    }
  }
#pragma unroll
  for (int m = 0; m < 4; ++m) {
#pragma unroll
    for (int j = 0; j < 4; ++j) {
      const int lr = wr * 64 + m * 16 + ((lane >> 4) << 2) + j;
      const int grow = row0 + lr;
      const int trow = tgt_s[lr];
      float s = 0.f;
#pragma unroll
      for (int n = 0; n < 4; ++n) {
        const int gcol = col0 + wc * 64 + n * 16 + (lane & 15);
        const float v = acc[m][n][j];
        if (gcol < C_) s += __expf(S_ * v);
        if (gcol == trow) tgt_logit[grow] = v;
      }
      s += __shfl_xor(s, 1); s += __shfl_xor(s, 2);
      s += __shfl_xor(s, 4); s += __shfl_xor(s, 8);
      if ((lane & 15) == 0) atomicAdd(&row_sum[grow], s);
    }
  }
}

// ---------------- 3) final arcface loss (multi-block, atomic accumulate) ----------------
__global__ __launch_bounds__(256) void loss_kernel(const float* __restrict__ row_sum,
                                                   const float* __restrict__ tgt_logit,
                                                   float* __restrict__ out) {
  __shared__ float red[4];
  const int i = blockIdx.x * 256 + threadIdx.x;
  const float tv = tgt_logit[i];
  const float tc = fminf(fmaxf(tv, -1.0f + EPS_), 1.0f - EPS_);
  const float num = S_ * cosf(acosf(tc) + M_);
  const float excl = row_sum[i] - __expf(S_ * tv);
  const float den = __expf(num) + excl;
  float acc = num - logf(den);
#pragma unroll
  for (int m = 1; m < 64; m <<= 1) acc += __shfl_xor(acc, m);
  if ((threadIdx.x & 63) == 0) red[threadIdx.x >> 6] = acc;
  __syncthreads();
  if (threadIdx.x == 0)
    atomicAdd(out, -(red[0] + red[1] + red[2] + red[3]) / (float)N_);
}

extern "C" void kernel_launch(void* const* d_in, const int* in_sizes, int n_in,
                              void* d_out, int out_size, void* d_ws, size_t ws_size,
                              hipStream_t stream) {
  const float* x = (const float*)d_in[0];
  const float* W = (const float*)d_in[1];
  const int* target = (const int*)d_in[2];
  float* out = (float*)d_out;

  float* row_sum = (float*)d_ws;                     // [4096]
  float* tgt_logit = row_sum + N_;                   // [4096]
  ushort* xnb = (ushort*)(row_sum + 2 * N_);         // bf16 [4096][512] = 4 MB
  ushort* Wb = xnb + (size_t)N_ * D_;                // bf16 [50000][512] = 51.2 MB

  const size_t need = 2 * N_ * sizeof(float) + (size_t)N_ * D_ * 2 + (size_t)C_ * D_ * 2;

  hipMemsetAsync(d_ws, 0, 2 * N_ * sizeof(float), stream);
  hipMemsetAsync(d_out, 0, sizeof(float), stream);
  norm_kernel<<<N_ / 4, 256, 0, stream>>>(x, xnb);
  if (ws_size >= need) {
    convw_kernel<<<2048, 256, 0, stream>>>(W, Wb);
    gemm_8ph<<<dim3(16, 196), 512, 0, stream>>>(xnb, Wb, target, row_sum, tgt_logit);
  } else {
    gemm_kernel<<<dim3(N_ / 128, (C_ + 127) / 128), 256, 0, stream>>>(
        xnb, W, target, row_sum, tgt_logit);
  }
  loss_kernel<<<N_ / 256, 256, 0, stream>>>(row_sum, tgt_logit, out);
}